// Round 1
// baseline (541.837 us; speedup 1.0000x reference)
//
#include <hip/hip_runtime.h>
#include <math.h>

// Sizes (fixed by the problem)
#define B_ 8
#define C_ 64
#define T_ 16
#define H_ 56
#define W_ 56
#define HW_ (H_ * W_)   // 3136
#define CR_ 16

// ---------------- helpers ----------------
__device__ __forceinline__ void atomicMaxF(float* addr, float v) {
    // Monotonic int encoding trick; valid for mixed signs, init must be -inf.
    if (v >= 0.f) atomicMax((int*)addr, __float_as_int(v));
    else          atomicMin((unsigned int*)addr, (unsigned int)__float_as_int(v));
}

// ---------------- K0: init pooled to -inf ----------------
__global__ void init_pooled_kernel(float* __restrict__ pooled) {
    pooled[threadIdx.x] = -INFINITY;   // 512 threads, 1 block
}

// ---------------- K1: spatial mean pool (+emb) -> xt[b,c,t] ----------------
__global__ __launch_bounds__(256) void pool_kernel(
    const float* __restrict__ x, const float* __restrict__ emb,
    const int* __restrict__ viewp, float* __restrict__ xt)
{
    int bc = blockIdx.x;            // b*64 + c, 512 blocks
    int c  = bc & 63;
    float embc = emb[viewp[0] * C_ + c];
    const float* base = x + (size_t)bc * (T_ * HW_);
    __shared__ float red[4];
    int lane = threadIdx.x & 63, wv = threadIdx.x >> 6;
    for (int t = 0; t < T_; ++t) {
        const float* p = base + t * HW_;
        float s = 0.f;
        for (int i = threadIdx.x; i < HW_; i += 256) s += p[i];
        #pragma unroll
        for (int off = 32; off > 0; off >>= 1) s += __shfl_down(s, off);
        if (lane == 0) red[wv] = s;
        __syncthreads();
        if (threadIdx.x == 0)
            xt[bc * T_ + t] = (red[0] + red[1] + red[2] + red[3]) * (1.f / HW_) + embc;
        __syncthreads();
    }
}

// ---------------- K2: RouteFuncMLP -> alpha[b,c,t] ----------------
__global__ __launch_bounds__(64) void route_kernel(
    const float* __restrict__ xt,
    const float* __restrict__ Wg, const float* __restrict__ bg,
    const float* __restrict__ Wa, const float* __restrict__ ba,
    const float* __restrict__ bng, const float* __restrict__ bnb,
    const float* __restrict__ bnm, const float* __restrict__ bnv,
    const float* __restrict__ Wb, float* __restrict__ alpha)
{
    __shared__ float z[C_][T_];      // xt + g broadcast
    __shared__ float gs[C_], ggs[C_];
    __shared__ float hs[CR_][T_ + 2]; // padded in t
    int b = blockIdx.x, c = threadIdx.x;   // 8 blocks x 64 threads

    float gsum = 0.f;
    for (int t = 0; t < T_; ++t) {
        float v = xt[(b * C_ + c) * T_ + t];
        z[c][t] = v;
        gsum += v;
    }
    gs[c] = gsum * (1.f / T_);
    __syncthreads();

    // 1x1 conv on global branch: gg[o] = Wg[o,:] . g + bg[o]
    float acc = bg[c];
    for (int i = 0; i < C_; ++i) acc = fmaf(Wg[c * C_ + i], gs[i], acc);
    ggs[c] = acc;
    __syncthreads();

    for (int t = 0; t < T_; ++t) z[c][t] += ggs[c];
    if (c < CR_) { hs[c][0] = 0.f; hs[c][T_ + 1] = 0.f; }
    __syncthreads();

    // conv1d (K=3, pad=1) C->Cr, then BN + relu
    {
        int r = c & 15, tg = c >> 4;     // 16 r x 4 t-groups
        for (int tt = 0; tt < 4; ++tt) {
            int t = tg * 4 + tt;
            float v = ba[r];
            for (int i = 0; i < C_; ++i) {
                const float* wa = Wa + (r * C_ + i) * 3;
                if (t > 0)      v = fmaf(z[i][t - 1], wa[0], v);
                                v = fmaf(z[i][t],     wa[1], v);
                if (t < T_ - 1) v = fmaf(z[i][t + 1], wa[2], v);
            }
            v = (v - bnm[r]) * rsqrtf(bnv[r] + 1e-5f);
            v = fmaf(v, bng[r], bnb[r]);
            hs[r][t + 1] = fmaxf(v, 0.f);
        }
    }
    __syncthreads();

    // conv1d (K=3, pad=1) Cr->C, +1.0
    for (int t = 0; t < T_; ++t) {
        float v = 1.f;
        for (int r = 0; r < CR_; ++r) {
            const float* wb = Wb + (c * CR_ + r) * 3;
            v = fmaf(hs[r][t],     wb[0], v);
            v = fmaf(hs[r][t + 1], wb[1], v);
            v = fmaf(hs[r][t + 2], wb[2], v);
        }
        alpha[(b * C_ + c) * T_ + t] = v;
    }
}

// ---------------- K3: fused scale + 3x3 conv + max-pool ----------------
// Grid: (B*T) * 14 blocks; each block: one (b,t) image, 4-row strip, all 64 c_out.
// Block = 256 threads = 4 waves. lane = c_out, wave = 14-col quarter.
// LDS tile: 16 ci x 6 rows x 58 cols of scaled input. All compute-phase LDS
// reads are wave-uniform (broadcast) -> no bank conflicts.
#define CI_BLK 16
#define LROWS 6
#define LCOLS 58
#define LDS_CI (LROWS * LCOLS)   // 348

__global__ __launch_bounds__(256) void conv_kernel(
    const float* __restrict__ x, const float* __restrict__ emb,
    const int* __restrict__ viewp, const float* __restrict__ alpha,
    const float* __restrict__ Wconv, float* __restrict__ pooled)
{
    __shared__ float lx[CI_BLK * LDS_CI];
    __shared__ float smax[256];

    int blk  = blockIdx.x;
    int bt   = blk / 14, hblk = blk % 14;
    int b    = bt >> 4, t = bt & 15;
    int h0   = hblk * 4;
    int tid  = threadIdx.x;
    int co   = tid & 63, q = tid >> 6;
    int view = viewp[0];

    float acc[4][14];
    #pragma unroll
    for (int r = 0; r < 4; ++r)
        #pragma unroll
        for (int j = 0; j < 14; ++j) acc[r][j] = 0.f;

    const float* xbase = x + ((size_t)(b * C_) * T_ + t) * HW_;

    for (int cb = 0; cb < C_ / CI_BLK; ++cb) {
        __syncthreads();
        // stage scaled input tile
        for (int e = tid; e < CI_BLK * LDS_CI; e += 256) {
            int ci  = e / LDS_CI;
            int rem = e - ci * LDS_CI;
            int row = rem / LCOLS;
            int col = rem - row * LCOLS;
            int cig = cb * CI_BLK + ci;
            int ih = h0 - 1 + row, iw = col - 1;
            float v = 0.f;
            if ((unsigned)ih < (unsigned)H_ && (unsigned)iw < (unsigned)W_) {
                float a = alpha[(b * C_ + cig) * T_ + t];
                v = (xbase[(size_t)cig * T_ * HW_ + ih * W_ + iw] + emb[view * C_ + cig]) * a;
            }
            lx[e] = v;
        }
        __syncthreads();
        // compute
        for (int ci = 0; ci < CI_BLK; ++ci) {
            float wgt[9];
            const float* wp = Wconv + ((co * C_) + cb * CI_BLK + ci) * 9;
            #pragma unroll
            for (int i = 0; i < 9; ++i) wgt[i] = wp[i];
            const float* lrow = lx + ci * LDS_CI + q * 14;
            #pragma unroll
            for (int row = 0; row < LROWS; ++row) {
                float xv[16];
                #pragma unroll
                for (int m = 0; m < 16; ++m) xv[m] = lrow[row * LCOLS + m];
                #pragma unroll
                for (int kh = 0; kh < 3; ++kh) {
                    int r = row - kh;
                    if (r >= 0 && r < 4) {
                        #pragma unroll
                        for (int j = 0; j < 14; ++j) {
                            acc[r][j] = fmaf(xv[j + 0], wgt[kh * 3 + 0], acc[r][j]);
                            acc[r][j] = fmaf(xv[j + 1], wgt[kh * 3 + 1], acc[r][j]);
                            acc[r][j] = fmaf(xv[j + 2], wgt[kh * 3 + 2], acc[r][j]);
                        }
                    }
                }
            }
        }
    }

    // fused max over this strip
    float m = -INFINITY;
    #pragma unroll
    for (int r = 0; r < 4; ++r)
        #pragma unroll
        for (int j = 0; j < 14; ++j) m = fmaxf(m, acc[r][j]);
    smax[tid] = m;
    __syncthreads();
    if (tid < 64) {
        float mm = fmaxf(fmaxf(smax[tid], smax[tid + 64]),
                         fmaxf(smax[tid + 128], smax[tid + 192]));
        atomicMaxF(&pooled[b * C_ + tid], mm);
    }
}

// ---------------- K4: classifier ----------------
__global__ void cls_kernel(const float* __restrict__ pooled,
                           const float* __restrict__ Wcls,
                           const float* __restrict__ bcls,
                           float* __restrict__ out)
{
    int i = threadIdx.x;
    if (i >= B_ * 10) return;
    int b = i / 10, k = i % 10;
    float v = bcls[k];
    for (int c = 0; c < C_; ++c) v = fmaf(pooled[b * C_ + c], Wcls[k * C_ + c], v);
    out[i] = v;
}

// ---------------- launcher ----------------
extern "C" void kernel_launch(void* const* d_in, const int* in_sizes, int n_in,
                              void* d_out, int out_size, void* d_ws, size_t ws_size,
                              hipStream_t stream)
{
    const float* x     = (const float*)d_in[0];
    const int*   view  = (const int*)  d_in[1];
    const float* emb   = (const float*)d_in[2];
    const float* Wg    = (const float*)d_in[3];
    const float* bg    = (const float*)d_in[4];
    const float* Wa    = (const float*)d_in[5];
    const float* ba    = (const float*)d_in[6];
    const float* bng   = (const float*)d_in[7];
    const float* bnb   = (const float*)d_in[8];
    const float* bnm   = (const float*)d_in[9];
    const float* bnv   = (const float*)d_in[10];
    const float* Wb    = (const float*)d_in[11];
    const float* Wconv = (const float*)d_in[12];
    const float* Wcls  = (const float*)d_in[13];
    const float* bcls  = (const float*)d_in[14];
    float* out = (float*)d_out;

    float* ws     = (float*)d_ws;
    float* xt     = ws;            // 8192 floats
    float* alpha  = ws + 8192;     // 8192 floats
    float* pooled = ws + 16384;    // 512 floats

    hipLaunchKernelGGL(init_pooled_kernel, dim3(1), dim3(512), 0, stream, pooled);
    hipLaunchKernelGGL(pool_kernel, dim3(B_ * C_), dim3(256), 0, stream, x, emb, view, xt);
    hipLaunchKernelGGL(route_kernel, dim3(B_), dim3(64), 0, stream,
                       xt, Wg, bg, Wa, ba, bng, bnb, bnm, bnv, Wb, alpha);
    hipLaunchKernelGGL(conv_kernel, dim3(B_ * T_ * 14), dim3(256), 0, stream,
                       x, emb, view, alpha, Wconv, pooled);
    hipLaunchKernelGGL(cls_kernel, dim3(1), dim3(128), 0, stream, pooled, Wcls, bcls, out);
}

// Round 2
// 216.106 us; speedup vs baseline: 2.5073x; 2.5073x over previous
//
#include <hip/hip_runtime.h>
#include <math.h>

// Sizes (fixed by the problem)
#define B_ 8
#define C_ 64
#define T_ 16
#define H_ 56
#define W_ 56
#define HW_ (H_ * W_)   // 3136
#define CR_ 16

typedef __attribute__((ext_vector_type(8))) short bf16x8;
typedef __attribute__((ext_vector_type(4))) float f32x4;

// ---------------- helpers ----------------
__device__ __forceinline__ void atomicMaxF(float* addr, float v) {
    if (v >= 0.f) atomicMax((int*)addr, __float_as_int(v));
    else          atomicMin((unsigned int*)addr, (unsigned int)__float_as_int(v));
}

__device__ __forceinline__ unsigned short f2bf(float f) {
    unsigned u = __float_as_uint(f);
    u += 0x7fffu + ((u >> 16) & 1u);   // round to nearest even
    return (unsigned short)(u >> 16);
}

// ---------------- K0: init pooled to -inf ----------------
__global__ void init_pooled_kernel(float* __restrict__ pooled) {
    pooled[threadIdx.x] = -INFINITY;   // 512 threads, 1 block
}

// ---------------- K1: spatial mean pool (+emb) -> xt[b,c,t] ----------------
__global__ __launch_bounds__(256) void pool_kernel(
    const float* __restrict__ x, const float* __restrict__ emb,
    const int* __restrict__ viewp, float* __restrict__ xt)
{
    int bc = blockIdx.x;            // b*64 + c, 512 blocks
    int c  = bc & 63;
    int lane = threadIdx.x & 63, wv = threadIdx.x >> 6;
    float embc = emb[viewp[0] * C_ + c];
    const float4* base = (const float4*)(x + (size_t)bc * (T_ * HW_));
    for (int tt = 0; tt < 4; ++tt) {
        int t = wv * 4 + tt;
        const float4* p = base + t * (HW_ / 4);   // 784 float4
        float s = 0.f;
        for (int i = lane; i < HW_ / 4; i += 64) {
            float4 v = p[i];
            s += (v.x + v.y) + (v.z + v.w);
        }
        #pragma unroll
        for (int off = 32; off > 0; off >>= 1) s += __shfl_down(s, off);
        if (lane == 0) xt[bc * T_ + t] = s * (1.f / HW_) + embc;
    }
}

// ---------------- K2: RouteFuncMLP -> alpha[b,c,t] ----------------
__global__ __launch_bounds__(64) void route_kernel(
    const float* __restrict__ xt,
    const float* __restrict__ Wg, const float* __restrict__ bg,
    const float* __restrict__ Wa, const float* __restrict__ ba,
    const float* __restrict__ bng, const float* __restrict__ bnb,
    const float* __restrict__ bnm, const float* __restrict__ bnv,
    const float* __restrict__ Wb, float* __restrict__ alpha)
{
    __shared__ float z[C_][T_];
    __shared__ float gs[C_], ggs[C_];
    __shared__ float hs[CR_][T_ + 2];
    int b = blockIdx.x, c = threadIdx.x;

    float gsum = 0.f;
    for (int t = 0; t < T_; ++t) {
        float v = xt[(b * C_ + c) * T_ + t];
        z[c][t] = v;
        gsum += v;
    }
    gs[c] = gsum * (1.f / T_);
    __syncthreads();

    float acc = bg[c];
    for (int i = 0; i < C_; ++i) acc = fmaf(Wg[c * C_ + i], gs[i], acc);
    ggs[c] = acc;
    __syncthreads();

    for (int t = 0; t < T_; ++t) z[c][t] += ggs[c];
    if (c < CR_) { hs[c][0] = 0.f; hs[c][T_ + 1] = 0.f; }
    __syncthreads();

    {
        int r = c & 15, tg = c >> 4;
        for (int tt = 0; tt < 4; ++tt) {
            int t = tg * 4 + tt;
            float v = ba[r];
            for (int i = 0; i < C_; ++i) {
                const float* wa = Wa + (r * C_ + i) * 3;
                if (t > 0)      v = fmaf(z[i][t - 1], wa[0], v);
                                v = fmaf(z[i][t],     wa[1], v);
                if (t < T_ - 1) v = fmaf(z[i][t + 1], wa[2], v);
            }
            v = (v - bnm[r]) * rsqrtf(bnv[r] + 1e-5f);
            v = fmaf(v, bng[r], bnb[r]);
            hs[r][t + 1] = fmaxf(v, 0.f);
        }
    }
    __syncthreads();

    for (int t = 0; t < T_; ++t) {
        float v = 1.f;
        for (int r = 0; r < CR_; ++r) {
            const float* wb = Wb + (c * CR_ + r) * 3;
            v = fmaf(hs[r][t],     wb[0], v);
            v = fmaf(hs[r][t + 1], wb[1], v);
            v = fmaf(hs[r][t + 2], wb[2], v);
        }
        alpha[(b * C_ + c) * T_ + t] = v;
    }
}

// ---------------- K2b: prepack Wconv -> MFMA A-fragment layout (bf16) ----
// packW element idx = ((kstep*4 + mtile)*64 + lane)*8 + j
//   kstep = (kh*3+kw)*2 + cih ; co = mtile*16 + (lane&15)
//   ci = cih*32 + (lane>>4)*8 + j ; tap = kh*3+kw
__global__ __launch_bounds__(256) void prepack_kernel(
    const float* __restrict__ Wconv, unsigned short* __restrict__ packW)
{
    int idx = blockIdx.x * 256 + threadIdx.x;   // 36864 total -> 144 blocks
    if (idx >= 64 * 576) return;
    int j     = idx & 7;
    int lane  = (idx >> 3) & 63;
    int mt    = (idx >> 9) & 3;
    int kstep = idx >> 11;          // 0..17
    int cih = kstep & 1, tap = kstep >> 1;
    int co = mt * 16 + (lane & 15);
    int ci = cih * 32 + (lane >> 4) * 8 + j;
    packW[idx] = f2bf(Wconv[(co * C_ + ci) * 9 + tap]);
}

// ---------------- K3: fused scale + 3x3 conv (MFMA) + max-pool ----------
// Block: one (b,t), 8-row strip, all 64 couts. 256 thr = 4 waves.
// N = 448 positions = 28 tiles of 16; wave handles 7 tiles.
// LDS input layout: [stored_row 0..9][chunk 0..7][col 0..57][8 ci] bf16
//   element index (bf16x8 units) = row*464 + chunk*58 + col
#define RROWS 8
#define LROWS2 10
#define LCOLS2 58
#define ROWE (8 * LCOLS2)          // 464 bf16x8 per stored row

__global__ __launch_bounds__(256, 2) void conv_mfma_kernel(
    const float* __restrict__ x, const float* __restrict__ emb,
    const int* __restrict__ viewp, const float* __restrict__ alpha,
    const unsigned short* __restrict__ packW, float* __restrict__ pooled)
{
    __shared__ bf16x8 ltile[LROWS2 * ROWE];     // 74240 B
    __shared__ float sscale[C_], soff[C_];
    __shared__ float smax[4][C_];

    int blk = blockIdx.x;
    int strip = blk % 7;
    int bt = blk / 7;
    int t = bt & 15, b = bt >> 4;
    int h0 = strip * RROWS;
    int tid = threadIdx.x;
    int lane = tid & 63, wv = tid >> 6;

    if (tid < C_) {
        float a = alpha[(b * C_ + tid) * T_ + t];
        sscale[tid] = a;
        soff[tid] = emb[viewp[0] * C_ + tid] * a;
    }
    __syncthreads();

    // ---- stage scaled bf16 input tile ----
    const float* xbase = x + ((size_t)b * C_ * T_ + t) * HW_;   // + ci*(T_*HW_)
    for (int e = tid; e < LROWS2 * LCOLS2; e += 256) {
        int row = e / LCOLS2, col = e - row * LCOLS2;
        int ir = h0 + row - 1, ic = col - 1;
        bool valid = ((unsigned)ir < (unsigned)H_) & ((unsigned)ic < (unsigned)W_);
        const float* xp = xbase + ir * W_ + ic;
        for (int ch = 0; ch < 8; ++ch) {
            bf16x8 hv;
            #pragma unroll
            for (int j = 0; j < 8; ++j) {
                int ci = ch * 8 + j;
                float v = 0.f;
                if (valid) v = fmaf(xp[(size_t)ci * (T_ * HW_)], sscale[ci], soff[ci]);
                hv[j] = (short)f2bf(v);
            }
            ltile[(row * 8 + ch) * LCOLS2 + col] = hv;
        }
    }
    __syncthreads();

    // ---- MFMA main loop ----
    int q = lane >> 4, li = lane & 15;
    int baddr[7];
    #pragma unroll
    for (int nt = 0; nt < 7; ++nt) {
        int p = (wv * 7 + nt) * 16 + li;
        int row = p / W_, col = p - row * W_;
        baddr[nt] = row * ROWE + q * LCOLS2 + col;
    }

    f32x4 acc[7][4];
    #pragma unroll
    for (int nt = 0; nt < 7; ++nt)
        #pragma unroll
        for (int mt = 0; mt < 4; ++mt)
            acc[nt][mt] = (f32x4){0.f, 0.f, 0.f, 0.f};

    const bf16x8* pw = (const bf16x8*)packW;   // frag idx = (kstep*4+mt)*64 + lane

    #pragma unroll
    for (int kh = 0; kh < 3; ++kh) {
        #pragma unroll
        for (int kw = 0; kw < 3; ++kw) {
            #pragma unroll
            for (int cih = 0; cih < 2; ++cih) {
                const int kstep = (kh * 3 + kw) * 2 + cih;
                const int boff = kh * ROWE + kw + cih * (4 * LCOLS2);
                bf16x8 af[4];
                #pragma unroll
                for (int mt = 0; mt < 4; ++mt)
                    af[mt] = pw[(kstep * 4 + mt) * 64 + lane];
                #pragma unroll
                for (int nt = 0; nt < 7; ++nt) {
                    bf16x8 bfr = ltile[baddr[nt] + boff];
                    #pragma unroll
                    for (int mt = 0; mt < 4; ++mt)
                        acc[nt][mt] = __builtin_amdgcn_mfma_f32_16x16x32_bf16(
                            af[mt], bfr, acc[nt][mt], 0, 0, 0);
                }
            }
        }
    }

    // ---- fused max-pool ----
    // lane holds D rows cout = mt*16 + q*4 + i, col = tile pos (li)
    float m[4][4];
    #pragma unroll
    for (int mt = 0; mt < 4; ++mt)
        #pragma unroll
        for (int i = 0; i < 4; ++i) {
            float v = acc[0][mt][i];
            #pragma unroll
            for (int nt = 1; nt < 7; ++nt) v = fmaxf(v, acc[nt][mt][i]);
            m[mt][i] = v;
        }
    // reduce across li (lane bits 0..3)
    #pragma unroll
    for (int off = 1; off < 16; off <<= 1)
        #pragma unroll
        for (int mt = 0; mt < 4; ++mt)
            #pragma unroll
            for (int i = 0; i < 4; ++i)
                m[mt][i] = fmaxf(m[mt][i], __shfl_xor(m[mt][i], off));
    if (li == 0) {
        #pragma unroll
        for (int mt = 0; mt < 4; ++mt)
            #pragma unroll
            for (int i = 0; i < 4; ++i)
                smax[wv][mt * 16 + q * 4 + i] = m[mt][i];
    }
    __syncthreads();
    if (tid < C_) {
        float mm = fmaxf(fmaxf(smax[0][tid], smax[1][tid]),
                         fmaxf(smax[2][tid], smax[3][tid]));
        atomicMaxF(&pooled[b * C_ + tid], mm);
    }
}

// ---------------- K4: classifier ----------------
__global__ void cls_kernel(const float* __restrict__ pooled,
                           const float* __restrict__ Wcls,
                           const float* __restrict__ bcls,
                           float* __restrict__ out)
{
    int i = threadIdx.x;
    if (i >= B_ * 10) return;
    int b = i / 10, k = i % 10;
    float v = bcls[k];
    for (int c = 0; c < C_; ++c) v = fmaf(pooled[b * C_ + c], Wcls[k * C_ + c], v);
    out[i] = v;
}

// ---------------- launcher ----------------
extern "C" void kernel_launch(void* const* d_in, const int* in_sizes, int n_in,
                              void* d_out, int out_size, void* d_ws, size_t ws_size,
                              hipStream_t stream)
{
    const float* x     = (const float*)d_in[0];
    const int*   view  = (const int*)  d_in[1];
    const float* emb   = (const float*)d_in[2];
    const float* Wg    = (const float*)d_in[3];
    const float* bg    = (const float*)d_in[4];
    const float* Wa    = (const float*)d_in[5];
    const float* ba    = (const float*)d_in[6];
    const float* bng   = (const float*)d_in[7];
    const float* bnb   = (const float*)d_in[8];
    const float* bnm   = (const float*)d_in[9];
    const float* bnv   = (const float*)d_in[10];
    const float* Wb    = (const float*)d_in[11];
    const float* Wconv = (const float*)d_in[12];
    const float* Wcls  = (const float*)d_in[13];
    const float* bcls  = (const float*)d_in[14];
    float* out = (float*)d_out;

    float* ws     = (float*)d_ws;
    float* xt     = ws;                         // 8192 floats
    float* alpha  = ws + 8192;                  // 8192 floats
    float* pooled = ws + 16384;                 // 512 floats
    unsigned short* packW = (unsigned short*)(ws + 16896);  // 36864 bf16

    hipLaunchKernelGGL(init_pooled_kernel, dim3(1), dim3(512), 0, stream, pooled);
    hipLaunchKernelGGL(prepack_kernel, dim3(144), dim3(256), 0, stream, Wconv, packW);
    hipLaunchKernelGGL(pool_kernel, dim3(B_ * C_), dim3(256), 0, stream, x, emb, view, xt);
    hipLaunchKernelGGL(route_kernel, dim3(B_), dim3(64), 0, stream,
                       xt, Wg, bg, Wa, ba, bng, bnb, bnm, bnv, Wb, alpha);
    hipLaunchKernelGGL(conv_mfma_kernel, dim3(B_ * T_ * 7), dim3(256), 0, stream,
                       x, emb, view, alpha, packW, pooled);
    hipLaunchKernelGGL(cls_kernel, dim3(1), dim3(128), 0, stream, pooled, Wcls, bcls, out);
}

// Round 3
// 139.539 us; speedup vs baseline: 3.8831x; 1.5487x over previous
//
#include <hip/hip_runtime.h>
#include <math.h>

// Sizes (fixed by the problem)
#define B_ 8
#define C_ 64
#define T_ 16
#define H_ 56
#define W_ 56
#define HW_ (H_ * W_)   // 3136
#define CR_ 16

typedef __attribute__((ext_vector_type(8))) short bf16x8;
typedef __attribute__((ext_vector_type(4))) float f32x4;

// ---------------- helpers ----------------
__device__ __forceinline__ void atomicMaxF(float* addr, float v) {
    if (v >= 0.f) atomicMax((int*)addr, __float_as_int(v));
    else          atomicMin((unsigned int*)addr, (unsigned int)__float_as_int(v));
}

__device__ __forceinline__ unsigned short f2bf(float f) {
    unsigned u = __float_as_uint(f);
    u += 0x7fffu + ((u >> 16) & 1u);   // round to nearest even
    return (unsigned short)(u >> 16);
}

__device__ __forceinline__ void gload_lds16(const void* g, void* l) {
    __builtin_amdgcn_global_load_lds(
        (const __attribute__((address_space(1))) unsigned int*)g,
        (__attribute__((address_space(3))) unsigned int*)l,
        16, 0, 0);
}

// ---------------- K0: init pooled to -inf ----------------
__global__ void init_pooled_kernel(float* __restrict__ pooled) {
    pooled[threadIdx.x] = -INFINITY;   // 512 threads, 1 block
}

// ---------------- K1: prep: xs = bf16(x+emb) padded, + fused mean-pool ----
// Grid: (b,t,chunk) = 128*8 = 1024 blocks, 256 threads.
// xs layout: [bt][chunk][58 rows][58 cols][8 ci] bf16 (zero borders).
// Also writes xt[b,c,t] = sum over HW of (x+emb)  (plain store, no atomics).
#define PRROWS 14
__global__ __launch_bounds__(256) void prep_kernel(
    const float* __restrict__ x, const float* __restrict__ emb,
    const int* __restrict__ viewp, unsigned short* __restrict__ xs,
    float* __restrict__ xt)
{
    __shared__ float lxf[8 * PRROWS * 60];   // 26880 B
    __shared__ float sred[4][8];
    int blk = blockIdx.x;
    int ch = blk & 7, bt = blk >> 3;
    int b = bt >> 4, t = bt & 15;
    int tid = threadIdx.x, lane = tid & 63, wv = tid >> 6;
    int view = viewp[0];

    float e[8];
    #pragma unroll
    for (int j = 0; j < 8; ++j) e[j] = emb[view * C_ + ch * 8 + j];

    unsigned short* xso = xs + ((size_t)bt * 8 + ch) * (58 * 58) * 8;

    // zero border rows (padded rows 0 and 57)
    for (int i = tid; i < 2 * 58; i += 256) {
        int r = (i < 58) ? 0 : 57, c = (i < 58) ? i : i - 58;
        *(bf16x8*)(xso + (r * 58 + c) * 8) = (bf16x8){0,0,0,0,0,0,0,0};
    }

    float psum[8];
    #pragma unroll
    for (int j = 0; j < 8; ++j) psum[j] = 0.f;

    const float* xb = x + ((size_t)(b * C_ + ch * 8) * T_ + t) * HW_;

    for (int g = 0; g < 4; ++g) {
        int r0 = g * PRROWS;
        __syncthreads();
        // load 8 planes x 14 rows x 56 cols (float4, coalesced)
        for (int i = tid; i < 8 * PRROWS * 14; i += 256) {
            int ci  = i / (PRROWS * 14);
            int rem = i - ci * (PRROWS * 14);
            int row = rem / 14, f4 = rem % 14;
            float4 v = *(const float4*)(xb + (size_t)ci * (T_ * HW_) + (r0 + row) * W_ + f4 * 4);
            v.x += e[ci]; v.y += e[ci]; v.z += e[ci]; v.w += e[ci];
            *(float4*)&lxf[(ci * PRROWS + row) * 60 + f4 * 4] = v;
        }
        __syncthreads();
        // emit interleaved bf16x8 (coalesced 16B stores)
        for (int p = tid; p < PRROWS * 58; p += 256) {
            int row = p / 58, col = p - row * 58;
            bf16x8 hv;
            if (col >= 1 && col <= 56) {
                #pragma unroll
                for (int j = 0; j < 8; ++j) {
                    float v = lxf[(j * PRROWS + row) * 60 + col - 1];
                    psum[j] += v;
                    hv[j] = (short)f2bf(v);
                }
            } else {
                hv = (bf16x8){0,0,0,0,0,0,0,0};
            }
            *(bf16x8*)(xso + ((size_t)(r0 + row + 1) * 58 + col) * 8) = hv;
        }
    }
    // reduce psum across threads -> xt (this block owns its 8 (b,ci,t) cells)
    #pragma unroll
    for (int j = 0; j < 8; ++j) {
        float s = psum[j];
        #pragma unroll
        for (int off = 32; off > 0; off >>= 1) s += __shfl_down(s, off);
        if (lane == 0) sred[wv][j] = s;
    }
    __syncthreads();
    if (tid < 8) {
        float s = sred[0][tid] + sred[1][tid] + sred[2][tid] + sred[3][tid];
        xt[((size_t)b * C_ + ch * 8 + tid) * T_ + t] = s;   // sum incl. emb
    }
}

// ---------------- K2: RouteFuncMLP -> alphaT[b,t,c] ----------------
__global__ __launch_bounds__(64) void route_kernel(
    const float* __restrict__ xt,
    const float* __restrict__ Wg, const float* __restrict__ bg,
    const float* __restrict__ Wa, const float* __restrict__ ba,
    const float* __restrict__ bng, const float* __restrict__ bnb,
    const float* __restrict__ bnm, const float* __restrict__ bnv,
    const float* __restrict__ Wb, float* __restrict__ alphaT)
{
    __shared__ float z[C_][T_];
    __shared__ float gs[C_], ggs[C_];
    __shared__ float hs[CR_][T_ + 2];
    int b = blockIdx.x, c = threadIdx.x;

    float gsum = 0.f;
    for (int t = 0; t < T_; ++t) {
        float v = xt[(b * C_ + c) * T_ + t] * (1.f / HW_);
        z[c][t] = v;
        gsum += v;
    }
    gs[c] = gsum * (1.f / T_);
    __syncthreads();

    float acc = bg[c];
    for (int i = 0; i < C_; ++i) acc = fmaf(Wg[c * C_ + i], gs[i], acc);
    ggs[c] = acc;
    __syncthreads();

    for (int t = 0; t < T_; ++t) z[c][t] += ggs[c];
    if (c < CR_) { hs[c][0] = 0.f; hs[c][T_ + 1] = 0.f; }
    __syncthreads();

    {
        int r = c & 15, tg = c >> 4;
        for (int tt = 0; tt < 4; ++tt) {
            int t = tg * 4 + tt;
            float v = ba[r];
            for (int i = 0; i < C_; ++i) {
                const float* wa = Wa + (r * C_ + i) * 3;
                if (t > 0)      v = fmaf(z[i][t - 1], wa[0], v);
                                v = fmaf(z[i][t],     wa[1], v);
                if (t < T_ - 1) v = fmaf(z[i][t + 1], wa[2], v);
            }
            v = (v - bnm[r]) * rsqrtf(bnv[r] + 1e-5f);
            v = fmaf(v, bng[r], bnb[r]);
            hs[r][t + 1] = fmaxf(v, 0.f);
        }
    }
    __syncthreads();

    for (int t = 0; t < T_; ++t) {
        float v = 1.f;
        for (int r = 0; r < CR_; ++r) {
            const float* wb = Wb + (c * CR_ + r) * 3;
            v = fmaf(hs[r][t],     wb[0], v);
            v = fmaf(hs[r][t + 1], wb[1], v);
            v = fmaf(hs[r][t + 2], wb[2], v);
        }
        alphaT[(b * T_ + t) * C_ + c] = v;
    }
}

// ---------------- K2b: prepack Wconv -> fp32 fragment order ----------
// packW0 element idx = ((kstep*4 + mtile)*64 + lane)*8 + j
//   kstep = (kh*3+kw)*2 + cih ; co = mtile*16 + (lane&15)
//   ci = cih*32 + (lane>>4)*8 + j ; tap = kh*3+kw
__global__ __launch_bounds__(256) void prepack_kernel(
    const float* __restrict__ Wconv, float* __restrict__ packW0)
{
    int idx = blockIdx.x * 256 + threadIdx.x;   // 36864 total -> 144 blocks
    if (idx >= 64 * 576) return;
    int j     = idx & 7;
    int lane  = (idx >> 3) & 63;
    int mt    = (idx >> 9) & 3;
    int kstep = idx >> 11;          // 0..17
    int cih = kstep & 1, tap = kstep >> 1;
    int co = mt * 16 + (lane & 15);
    int ci = cih * 32 + (lane >> 4) * 8 + j;
    packW0[idx] = Wconv[(co * C_ + ci) * 9 + tap];
}

// ---------------- K2c: scale weights per (b,t) -> bf16 fragments -----
__global__ __launch_bounds__(256) void wscale_kernel(
    const float* __restrict__ packW0, const float* __restrict__ alphaT,
    unsigned short* __restrict__ packWbt)
{
    __shared__ float sal[C_];
    int bt = blockIdx.x, tid = threadIdx.x;
    if (tid < C_) sal[tid] = alphaT[bt * C_ + tid];
    __syncthreads();
    for (int f = tid; f < 4608; f += 256) {        // (kstep,mt,lane) frags
        int lane = f & 63, kstep = f >> 8;
        int cibase = (kstep & 1) * 32 + ((lane >> 4)) * 8;
        const float* w = packW0 + (size_t)f * 8;
        bf16x8 hv;
        #pragma unroll
        for (int j = 0; j < 8; ++j) hv[j] = (short)f2bf(w[j] * sal[cibase + j]);
        *(bf16x8*)(packWbt + (size_t)bt * 36864 + (size_t)f * 8) = hv;
    }
}

// ---------------- K3: conv (MFMA) + max-pool; staging via global_load_lds
// Block: one (b,t), 8-row strip, all 64 couts. 256 thr = 4 waves.
// LDS: [stored_row 0..9][chunk 0..7][col 0..57][8 ci] bf16
#define RROWS 8
#define LROWS2 10
#define LCOLS2 58
#define ROWE (8 * LCOLS2)          // 464 bf16x8 per stored row

__global__ __launch_bounds__(256) void conv_mfma_kernel(
    const unsigned short* __restrict__ xs,
    const unsigned short* __restrict__ packWbt,
    float* __restrict__ pooled)
{
    __shared__ bf16x8 ltile[LROWS2 * ROWE];     // 74240 B
    __shared__ float smax[4][C_];

    int blk = blockIdx.x;
    int strip = blk % 7;
    int bt = blk / 7;
    int b = bt >> 4;
    int h0 = strip * RROWS;
    int tid = threadIdx.x;
    int lane = tid & 63, wv = tid >> 6;

    // ---- stage: 80 row-segments of 58 x 16B via async DMA ----
    const unsigned short* xsbt = xs + (size_t)bt * (8 * 3364 * 8);
    for (int s = wv; s < 80; s += 4) {
        int row = s >> 3, ch = s & 7;
        const unsigned short* src =
            xsbt + ((size_t)ch * 3364 + (size_t)(h0 + row) * 58 + lane) * 8;
        if (lane < 58)
            gload_lds16(src, &ltile[(row * 8 + ch) * LCOLS2]);
    }
    __syncthreads();

    // ---- MFMA main loop ----
    int q = lane >> 4, li = lane & 15;
    int baddr[7];
    #pragma unroll
    for (int nt = 0; nt < 7; ++nt) {
        int p = (wv * 7 + nt) * 16 + li;
        int row = p / W_, col = p - row * W_;
        baddr[nt] = row * ROWE + q * LCOLS2 + col;
    }

    f32x4 acc[7][4];
    #pragma unroll
    for (int nt = 0; nt < 7; ++nt)
        #pragma unroll
        for (int mt = 0; mt < 4; ++mt)
            acc[nt][mt] = (f32x4){0.f, 0.f, 0.f, 0.f};

    const bf16x8* pw = (const bf16x8*)(packWbt + (size_t)bt * 36864);

    #pragma unroll
    for (int kh = 0; kh < 3; ++kh) {
        #pragma unroll
        for (int kw = 0; kw < 3; ++kw) {
            #pragma unroll
            for (int cih = 0; cih < 2; ++cih) {
                const int kstep = (kh * 3 + kw) * 2 + cih;
                const int boff = kh * ROWE + kw + cih * (4 * LCOLS2);
                bf16x8 af[4];
                #pragma unroll
                for (int mt = 0; mt < 4; ++mt)
                    af[mt] = pw[(kstep * 4 + mt) * 64 + lane];
                #pragma unroll
                for (int nt = 0; nt < 7; ++nt) {
                    bf16x8 bfr = ltile[baddr[nt] + boff];
                    #pragma unroll
                    for (int mt = 0; mt < 4; ++mt)
                        acc[nt][mt] = __builtin_amdgcn_mfma_f32_16x16x32_bf16(
                            af[mt], bfr, acc[nt][mt], 0, 0, 0);
                }
            }
        }
    }

    // ---- fused max-pool ----
    float m[4][4];
    #pragma unroll
    for (int mt = 0; mt < 4; ++mt)
        #pragma unroll
        for (int i = 0; i < 4; ++i) {
            float v = acc[0][mt][i];
            #pragma unroll
            for (int nt = 1; nt < 7; ++nt) v = fmaxf(v, acc[nt][mt][i]);
            m[mt][i] = v;
        }
    #pragma unroll
    for (int off = 1; off < 16; off <<= 1)
        #pragma unroll
        for (int mt = 0; mt < 4; ++mt)
            #pragma unroll
            for (int i = 0; i < 4; ++i)
                m[mt][i] = fmaxf(m[mt][i], __shfl_xor(m[mt][i], off));
    if (li == 0) {
        #pragma unroll
        for (int mt = 0; mt < 4; ++mt)
            #pragma unroll
            for (int i = 0; i < 4; ++i)
                smax[wv][mt * 16 + q * 4 + i] = m[mt][i];
    }
    __syncthreads();
    if (tid < C_) {
        float mm = fmaxf(fmaxf(smax[0][tid], smax[1][tid]),
                         fmaxf(smax[2][tid], smax[3][tid]));
        atomicMaxF(&pooled[b * C_ + tid], mm);
    }
}

// ---------------- K4: classifier ----------------
__global__ void cls_kernel(const float* __restrict__ pooled,
                           const float* __restrict__ Wcls,
                           const float* __restrict__ bcls,
                           float* __restrict__ out)
{
    int i = threadIdx.x;
    if (i >= B_ * 10) return;
    int b = i / 10, k = i % 10;
    float v = bcls[k];
    for (int c = 0; c < C_; ++c) v = fmaf(pooled[b * C_ + c], Wcls[k * C_ + c], v);
    out[i] = v;
}

// ---------------- launcher ----------------
extern "C" void kernel_launch(void* const* d_in, const int* in_sizes, int n_in,
                              void* d_out, int out_size, void* d_ws, size_t ws_size,
                              hipStream_t stream)
{
    const float* x     = (const float*)d_in[0];
    const int*   view  = (const int*)  d_in[1];
    const float* emb   = (const float*)d_in[2];
    const float* Wg    = (const float*)d_in[3];
    const float* bg    = (const float*)d_in[4];
    const float* Wa    = (const float*)d_in[5];
    const float* ba    = (const float*)d_in[6];
    const float* bng   = (const float*)d_in[7];
    const float* bnb   = (const float*)d_in[8];
    const float* bnm   = (const float*)d_in[9];
    const float* bnv   = (const float*)d_in[10];
    const float* Wb    = (const float*)d_in[11];
    const float* Wconv = (const float*)d_in[12];
    const float* Wcls  = (const float*)d_in[13];
    const float* bcls  = (const float*)d_in[14];
    float* out = (float*)d_out;

    char* wsb = (char*)d_ws;
    float*          xt      = (float*)(wsb + 0);               // 32768 B
    float*          alphaT  = (float*)(wsb + 32768);           // 32768 B
    float*          pooled  = (float*)(wsb + 65536);           // 2048 B
    float*          packW0  = (float*)(wsb + 67584);           // 147456 B
    unsigned short* packWbt = (unsigned short*)(wsb + 215040); // 9437184 B
    unsigned short* xs      = (unsigned short*)(wsb + 9652224);// 55115776 B

    hipLaunchKernelGGL(init_pooled_kernel, dim3(1), dim3(512), 0, stream, pooled);
    hipLaunchKernelGGL(prepack_kernel, dim3(144), dim3(256), 0, stream, Wconv, packW0);
    hipLaunchKernelGGL(prep_kernel, dim3(1024), dim3(256), 0, stream, x, emb, view, xs, xt);
    hipLaunchKernelGGL(route_kernel, dim3(B_), dim3(64), 0, stream,
                       xt, Wg, bg, Wa, ba, bng, bnb, bnm, bnv, Wb, alphaT);
    hipLaunchKernelGGL(wscale_kernel, dim3(B_ * T_), dim3(256), 0, stream,
                       packW0, alphaT, packWbt);
    hipLaunchKernelGGL(conv_mfma_kernel, dim3(B_ * T_ * 7), dim3(256), 0, stream,
                       xs, packWbt, pooled);
    hipLaunchKernelGGL(cls_kernel, dim3(1), dim3(128), 0, stream, pooled, Wcls, bcls, out);
}

// Round 4
// 97.443 us; speedup vs baseline: 5.5606x; 1.4320x over previous
//
#include <hip/hip_runtime.h>
#include <math.h>

// Sizes (fixed by the problem)
#define B_ 8
#define C_ 64
#define T_ 16
#define H_ 56
#define W_ 56
#define HW_ (H_ * W_)   // 3136
#define CR_ 16

typedef __attribute__((ext_vector_type(8))) short bf16x8;
typedef __attribute__((ext_vector_type(4))) float f32x4;

// ---------------- helpers ----------------
__device__ __forceinline__ void atomicMaxF(float* addr, float v) {
    if (v >= 0.f) atomicMax((int*)addr, __float_as_int(v));
    else          atomicMin((unsigned int*)addr, (unsigned int)__float_as_int(v));
}

__device__ __forceinline__ unsigned short f2bf(float f) {
    unsigned u = __float_as_uint(f);
    u += 0x7fffu + ((u >> 16) & 1u);   // round to nearest even
    return (unsigned short)(u >> 16);
}

__device__ __forceinline__ void gload_lds16(const void* g, void* l) {
    __builtin_amdgcn_global_load_lds(
        (const __attribute__((address_space(1))) unsigned int*)g,
        (__attribute__((address_space(3))) unsigned int*)l,
        16, 0, 0);
}

// ---------------- K1: prep: xs = bf16(x+emb) padded + fused mean-pool ----
// Grid: (bt, ch) = 1024 blocks, 256 threads = 4 waves.
// Register transpose: lane = col, gathers its 8 ci values (each load is
// coalesced across lanes within one ci plane). No LDS for data.
// xs layout: [bt][ch][58 rows][58 cols][8 ci] bf16, zero borders.
__global__ __launch_bounds__(256) void prep_kernel(
    const float* __restrict__ x, const float* __restrict__ emb,
    const int* __restrict__ viewp, unsigned short* __restrict__ xs,
    float* __restrict__ xt)
{
    __shared__ float sred[4][8];
    int blk = blockIdx.x;
    int ch = blk & 7, bt = blk >> 3;
    int b = bt >> 4, t = bt & 15;
    int tid = threadIdx.x, lane = tid & 63, wv = tid >> 6;
    int view = viewp[0];

    float e[8];
    #pragma unroll
    for (int j = 0; j < 8; ++j) e[j] = emb[view * C_ + ch * 8 + j];

    const float* xb = x + ((size_t)(b * C_ + ch * 8) * T_ + t) * HW_;
    unsigned short* xso = xs + ((size_t)bt * 8 + ch) * (58 * 58) * 8;

    // zero borders: rows 0,57 (58 each) + cols 0,57 of rows 1..56 (56 each)
    for (int i = tid; i < 228; i += 256) {
        int r, c;
        if (i < 58)       { r = 0;            c = i; }
        else if (i < 116) { r = 57;           c = i - 58; }
        else if (i < 172) { r = i - 116 + 1;  c = 0; }
        else              { r = i - 172 + 1;  c = 57; }
        *(bf16x8*)(xso + ((size_t)r * 58 + c) * 8) = (bf16x8){0,0,0,0,0,0,0,0};
    }

    float psum[8];
    #pragma unroll
    for (int j = 0; j < 8; ++j) psum[j] = 0.f;

    if (lane < 56) {
        #pragma unroll 2
        for (int rr = 0; rr < 14; ++rr) {
            int row = wv * 14 + rr;
            const float* p = xb + row * W_ + lane;
            float v[8];
            #pragma unroll
            for (int j = 0; j < 8; ++j) v[j] = p[(size_t)j * (T_ * HW_)] + e[j];
            bf16x8 hv;
            #pragma unroll
            for (int j = 0; j < 8; ++j) { psum[j] += v[j]; hv[j] = (short)f2bf(v[j]); }
            *(bf16x8*)(xso + ((size_t)(row + 1) * 58 + (lane + 1)) * 8) = hv;
        }
    }

    // reduce psum (lanes >=56 hold zeros) -> xt[b, ch*8+j, t] (sum incl emb)
    #pragma unroll
    for (int j = 0; j < 8; ++j) {
        float s = psum[j];
        #pragma unroll
        for (int off = 32; off > 0; off >>= 1) s += __shfl_down(s, off);
        if (lane == 0) sred[wv][j] = s;
    }
    __syncthreads();
    if (tid < 8) {
        float s = sred[0][tid] + sred[1][tid] + sred[2][tid] + sred[3][tid];
        xt[((size_t)b * C_ + ch * 8 + tid) * T_ + t] = s;
    }
}

// ---------------- K2: RouteFuncMLP -> alphaT[b,t,c] (LDS-staged) --------
__global__ __launch_bounds__(256) void route_kernel(
    const float* __restrict__ xt,
    const float* __restrict__ Wg, const float* __restrict__ bg,
    const float* __restrict__ Wa, const float* __restrict__ ba,
    const float* __restrict__ bng, const float* __restrict__ bnb,
    const float* __restrict__ bnm, const float* __restrict__ bnv,
    const float* __restrict__ Wb, float* __restrict__ alphaT)
{
    __shared__ float swg[64 * 65];   // Wg[c][i] at c*65+i (pad 65: no conflicts)
    __shared__ float swa[64 * 48];   // Wa[r][i][tap] at i*48 + r*3 + tap
    __shared__ float swb[48 * 64];   // Wb[c][r][tap] at (r*3+tap)*64 + c
    __shared__ float z[64 * 18];     // z[i][tslot], tslot = t+1 (0,17 = zero pad)
    __shared__ float gs[64], ggs[64];
    __shared__ float hs[16][18];     // hs[r][tslot]
    int b = blockIdx.x, tid = threadIdx.x;

    for (int idx = tid; idx < 4096; idx += 256) {
        int c = idx >> 6, i = idx & 63;
        swg[c * 65 + i] = Wg[idx];
    }
    for (int idx = tid; idx < 3072; idx += 256) {
        int r = idx / 192, rem = idx % 192;   // global Wa[r][i][tap]
        int i = rem / 3, tap = rem % 3;
        swa[i * 48 + r * 3 + tap] = Wa[idx];
    }
    for (int idx = tid; idx < 3072; idx += 256) {
        int k = idx >> 6, c = idx & 63;       // lds idx = k*64+c
        swb[idx] = Wb[c * 48 + k];
    }
    for (int idx = tid; idx < 1024; idx += 256) {
        int c = idx >> 4, t = idx & 15;
        z[c * 18 + t + 1] = xt[b * 1024 + idx] * (1.f / HW_);
    }
    if (tid < 64) { z[tid * 18] = 0.f; z[tid * 18 + 17] = 0.f; }
    if (tid < 16) { hs[tid][0] = 0.f; hs[tid][17] = 0.f; }
    __syncthreads();

    if (tid < 64) {
        float s = 0.f;
        #pragma unroll
        for (int t = 1; t <= 16; ++t) s += z[tid * 18 + t];
        gs[tid] = s * (1.f / 16.f);
    }
    __syncthreads();
    if (tid < 64) {
        float acc = bg[tid];
        #pragma unroll 8
        for (int i = 0; i < 64; ++i) acc = fmaf(swg[tid * 65 + i], gs[i], acc);
        ggs[tid] = acc;
    }
    __syncthreads();
    for (int idx = tid; idx < 1024; idx += 256) {
        int c = idx >> 4, t = idx & 15;
        z[c * 18 + t + 1] += ggs[c];
    }
    __syncthreads();

    // first conv (C->Cr) + BN + relu: one (r,t) per thread
    {
        int t = tid >> 4, r = tid & 15;
        float v = ba[r];
        #pragma unroll 8
        for (int i = 0; i < 64; ++i) {
            const float* wa = &swa[i * 48 + r * 3];
            const float* zz = &z[i * 18 + t];
            v = fmaf(zz[0], wa[0], v);
            v = fmaf(zz[1], wa[1], v);
            v = fmaf(zz[2], wa[2], v);
        }
        v = (v - bnm[r]) * rsqrtf(bnv[r] + 1e-5f);
        v = fmaf(v, bng[r], bnb[r]);
        hs[r][t + 1] = fmaxf(v, 0.f);
    }
    __syncthreads();

    // second conv (Cr->C), +1: idx = t*64 + c (coalesced LDS + global store)
    for (int idx = tid; idx < 1024; idx += 256) {
        int t = idx >> 6, c = idx & 63;
        float v = 1.f;
        #pragma unroll
        for (int r = 0; r < 16; ++r) {
            v = fmaf(hs[r][t],     swb[(r * 3 + 0) * 64 + c], v);
            v = fmaf(hs[r][t + 1], swb[(r * 3 + 1) * 64 + c], v);
            v = fmaf(hs[r][t + 2], swb[(r * 3 + 2) * 64 + c], v);
        }
        alphaT[(b * T_ + t) * C_ + c] = v;
    }
}

// ---------------- K2b: prepack Wconv -> fp32 fragment order + pooled init
__global__ __launch_bounds__(256) void prepack_kernel(
    const float* __restrict__ Wconv, float* __restrict__ packW0,
    float* __restrict__ pooled)
{
    int idx = blockIdx.x * 256 + threadIdx.x;   // 144 blocks
    if (idx < 512) pooled[idx] = -INFINITY;
    if (idx >= 64 * 576) return;
    int j     = idx & 7;
    int lane  = (idx >> 3) & 63;
    int mt    = (idx >> 9) & 3;
    int kstep = idx >> 11;          // 0..17
    int cih = kstep & 1, tap = kstep >> 1;
    int co = mt * 16 + (lane & 15);
    int ci = cih * 32 + (lane >> 4) * 8 + j;
    packW0[idx] = Wconv[(co * C_ + ci) * 9 + tap];
}

// ---------------- K2c: scale weights per (b,t) -> bf16 fragments -----
__global__ __launch_bounds__(256) void wscale_kernel(
    const float* __restrict__ packW0, const float* __restrict__ alphaT,
    unsigned short* __restrict__ packWbt)
{
    __shared__ float sal[C_];
    int bt = blockIdx.x, tid = threadIdx.x;
    if (tid < C_) sal[tid] = alphaT[bt * C_ + tid];
    __syncthreads();
    for (int f = tid; f < 4608; f += 256) {        // (kstep,mt,lane) frags
        int lane = f & 63, kstep = f >> 8;
        int cibase = (kstep & 1) * 32 + ((lane >> 4)) * 8;
        const float* w = packW0 + (size_t)f * 8;
        bf16x8 hv;
        #pragma unroll
        for (int j = 0; j < 8; ++j) hv[j] = (short)f2bf(w[j] * sal[cibase + j]);
        *(bf16x8*)(packWbt + (size_t)bt * 36864 + (size_t)f * 8) = hv;
    }
}

// ---------------- K3: conv (MFMA) + max-pool; staging via global_load_lds
#define RROWS 8
#define LROWS2 10
#define LCOLS2 58
#define ROWE (8 * LCOLS2)          // 464 bf16x8 per stored row

__global__ __launch_bounds__(256) void conv_mfma_kernel(
    const unsigned short* __restrict__ xs,
    const unsigned short* __restrict__ packWbt,
    float* __restrict__ pooled)
{
    __shared__ bf16x8 ltile[LROWS2 * ROWE];     // 74240 B
    __shared__ float smax[4][C_];

    int blk = blockIdx.x;
    int strip = blk % 7;
    int bt = blk / 7;
    int b = bt >> 4;
    int h0 = strip * RROWS;
    int tid = threadIdx.x;
    int lane = tid & 63, wv = tid >> 6;

    // ---- stage: 80 row-segments of 58 x 16B via async DMA ----
    const unsigned short* xsbt = xs + (size_t)bt * (8 * 3364 * 8);
    for (int s = wv; s < 80; s += 4) {
        int row = s >> 3, ch = s & 7;
        const unsigned short* src =
            xsbt + ((size_t)ch * 3364 + (size_t)(h0 + row) * 58 + lane) * 8;
        if (lane < 58)
            gload_lds16(src, &ltile[(row * 8 + ch) * LCOLS2]);
    }
    __syncthreads();

    // ---- MFMA main loop ----
    int q = lane >> 4, li = lane & 15;
    int baddr[7];
    #pragma unroll
    for (int nt = 0; nt < 7; ++nt) {
        int p = (wv * 7 + nt) * 16 + li;
        int row = p / W_, col = p - row * W_;
        baddr[nt] = row * ROWE + q * LCOLS2 + col;
    }

    f32x4 acc[7][4];
    #pragma unroll
    for (int nt = 0; nt < 7; ++nt)
        #pragma unroll
        for (int mt = 0; mt < 4; ++mt)
            acc[nt][mt] = (f32x4){0.f, 0.f, 0.f, 0.f};

    const bf16x8* pw = (const bf16x8*)(packWbt + (size_t)bt * 36864);

    #pragma unroll
    for (int kh = 0; kh < 3; ++kh) {
        #pragma unroll
        for (int kw = 0; kw < 3; ++kw) {
            #pragma unroll
            for (int cih = 0; cih < 2; ++cih) {
                const int kstep = (kh * 3 + kw) * 2 + cih;
                const int boff = kh * ROWE + kw + cih * (4 * LCOLS2);
                bf16x8 af[4];
                #pragma unroll
                for (int mt = 0; mt < 4; ++mt)
                    af[mt] = pw[(kstep * 4 + mt) * 64 + lane];
                #pragma unroll
                for (int nt = 0; nt < 7; ++nt) {
                    bf16x8 bfr = ltile[baddr[nt] + boff];
                    #pragma unroll
                    for (int mt = 0; mt < 4; ++mt)
                        acc[nt][mt] = __builtin_amdgcn_mfma_f32_16x16x32_bf16(
                            af[mt], bfr, acc[nt][mt], 0, 0, 0);
                }
            }
        }
    }

    // ---- fused max-pool ----
    float m[4][4];
    #pragma unroll
    for (int mt = 0; mt < 4; ++mt)
        #pragma unroll
        for (int i = 0; i < 4; ++i) {
            float v = acc[0][mt][i];
            #pragma unroll
            for (int nt = 1; nt < 7; ++nt) v = fmaxf(v, acc[nt][mt][i]);
            m[mt][i] = v;
        }
    #pragma unroll
    for (int off = 1; off < 16; off <<= 1)
        #pragma unroll
        for (int mt = 0; mt < 4; ++mt)
            #pragma unroll
            for (int i = 0; i < 4; ++i)
                m[mt][i] = fmaxf(m[mt][i], __shfl_xor(m[mt][i], off));
    if (li == 0) {
        #pragma unroll
        for (int mt = 0; mt < 4; ++mt)
            #pragma unroll
            for (int i = 0; i < 4; ++i)
                smax[wv][mt * 16 + q * 4 + i] = m[mt][i];
    }
    __syncthreads();
    if (tid < C_) {
        float mm = fmaxf(fmaxf(smax[0][tid], smax[1][tid]),
                         fmaxf(smax[2][tid], smax[3][tid]));
        atomicMaxF(&pooled[b * C_ + tid], mm);
    }
}

// ---------------- K4: classifier ----------------
__global__ void cls_kernel(const float* __restrict__ pooled,
                           const float* __restrict__ Wcls,
                           const float* __restrict__ bcls,
                           float* __restrict__ out)
{
    int i = threadIdx.x;
    if (i >= B_ * 10) return;
    int b = i / 10, k = i % 10;
    float v = bcls[k];
    for (int c = 0; c < C_; ++c) v = fmaf(pooled[b * C_ + c], Wcls[k * C_ + c], v);
    out[i] = v;
}

// ---------------- launcher ----------------
extern "C" void kernel_launch(void* const* d_in, const int* in_sizes, int n_in,
                              void* d_out, int out_size, void* d_ws, size_t ws_size,
                              hipStream_t stream)
{
    const float* x     = (const float*)d_in[0];
    const int*   view  = (const int*)  d_in[1];
    const float* emb   = (const float*)d_in[2];
    const float* Wg    = (const float*)d_in[3];
    const float* bg    = (const float*)d_in[4];
    const float* Wa    = (const float*)d_in[5];
    const float* ba    = (const float*)d_in[6];
    const float* bng   = (const float*)d_in[7];
    const float* bnb   = (const float*)d_in[8];
    const float* bnm   = (const float*)d_in[9];
    const float* bnv   = (const float*)d_in[10];
    const float* Wb    = (const float*)d_in[11];
    const float* Wconv = (const float*)d_in[12];
    const float* Wcls  = (const float*)d_in[13];
    const float* bcls  = (const float*)d_in[14];
    float* out = (float*)d_out;

    char* wsb = (char*)d_ws;
    float*          xt      = (float*)(wsb + 0);               // 32768 B
    float*          alphaT  = (float*)(wsb + 32768);           // 32768 B
    float*          pooled  = (float*)(wsb + 65536);           // 2048 B
    float*          packW0  = (float*)(wsb + 67584);           // 147456 B
    unsigned short* packWbt = (unsigned short*)(wsb + 215040); // 9437184 B
    unsigned short* xs      = (unsigned short*)(wsb + 9652224);// 55115776 B

    hipLaunchKernelGGL(prepack_kernel, dim3(144), dim3(256), 0, stream,
                       Wconv, packW0, pooled);
    hipLaunchKernelGGL(prep_kernel, dim3(1024), dim3(256), 0, stream,
                       x, emb, view, xs, xt);
    hipLaunchKernelGGL(route_kernel, dim3(B_), dim3(256), 0, stream,
                       xt, Wg, bg, Wa, ba, bng, bnb, bnm, bnv, Wb, alphaT);
    hipLaunchKernelGGL(wscale_kernel, dim3(B_ * T_), dim3(256), 0, stream,
                       packW0, alphaT, packWbt);
    hipLaunchKernelGGL(conv_mfma_kernel, dim3(B_ * T_ * 7), dim3(256), 0, stream,
                       xs, packWbt, pooled);
    hipLaunchKernelGGL(cls_kernel, dim3(1), dim3(128), 0, stream, pooled, Wcls, bcls, out);
}